// Round 5
// baseline (215.528 us; speedup 1.0000x reference)
//
#include <hip/hip_runtime.h>
#include <hip/hip_bf16.h>

#define NN 128
#define DD 128

typedef __attribute__((ext_vector_type(8))) short bf16x8;
typedef __attribute__((ext_vector_type(4))) float floatx4;
typedef __attribute__((ext_vector_type(2))) float floatx2;

__device__ __forceinline__ unsigned short f2bf(float f) {
    // round-to-nearest-even bf16 (finite inputs only)
    unsigned int bits = __float_as_uint(f);
    unsigned int r = bits + 0x7FFFu + ((bits >> 16) & 1u);
    return (unsigned short)(r >> 16);
}

__device__ __forceinline__ unsigned short f2bf_hw(float f) {
    unsigned int r;
    asm("v_cvt_pk_bf16_f32 %0, %1, %2" : "=v"(r) : "v"(f), "v"(f));
    return (unsigned short)r;
}

__device__ __forceinline__ unsigned int f2bf_pk(float lo, float hi) {
    unsigned int r;
    asm("v_cvt_pk_bf16_f32 %0, %1, %2" : "=v"(r) : "v"(lo), "v"(hi));
    return r;
}

// ws layout (float units)
#define WS_HJB0 0        // 8*128*128 bf16 = 65536 f   (Hjb exchange ping)
#define WS_HJB1 65536    // (pong)
#define WS_W1T  131072   // 34816 ushorts: w1t[n][d] = W1[n&127][(n>>7)*128+d], stride 136
#define WS_W2B  148480   // 17408 ushorts: w2b[e][d] = W2[e][d], stride 136
#define WS_CNT  157184   // 8 batches x 5 rounds x 32 ints (1 cacheline per counter)

// ---------------- K_init: weight images + barrier counters (all parallel) ----------------
__global__ __launch_bounds__(256) void k_init(const float* __restrict__ W1f,
                                              const float* __restrict__ W2f,
                                              float* __restrict__ ws) {
    unsigned short* gw1t = (unsigned short*)(ws + WS_W1T);
    unsigned short* gw2b = (unsigned short*)(ws + WS_W2B);
    int* cnt = (int*)(ws + WS_CNT);
    int blk = blockIdx.x, t = threadIdx.x;
    if (blk < 9) {                        // gw1t (256x136): B[n][d] = W1[n&127][(n>>7)*128+d]
        int base = blk * 4096;
#pragma unroll
        for (int it = 0; it < 16; ++it) {
            int idx = base + it * 256 + t;
            if (idx < 256 * 136) {
                int e = idx / 136, d = idx - e * 136;
                gw1t[idx] = (d < 128) ? f2bf(W1f[(e & 127) * 256 + (e >> 7) * 128 + d])
                                      : (unsigned short)0;
            }
        }
    } else if (blk < 14) {                // gw2b (128x136): W2[e][d]
        int base = (blk - 9) * 4096;
#pragma unroll
        for (int it = 0; it < 16; ++it) {
            int idx = base + it * 256 + t;
            if (idx < 128 * 136) {
                int e = idx / 136, d = idx - e * 136;
                gw2b[idx] = (d < 128) ? f2bf(W2f[e * 128 + d]) : (unsigned short)0;
            }
        }
    } else {                              // blk == 14: zero barrier counters (8*5*32 ints)
#pragma unroll
        for (int it = 0; it < 5; ++it) cnt[it * 256 + t] = 0;
    }
}

// ---------------- K_main: 5 rounds + head. 256 blocks x 1024 threads (16 waves), 1/CU -----
// NOTE: __launch_bounds__(1024) with NO min-waves arg: a 1024-thread block needs 16 resident
// waves -> backend caps VGPR at 128. (1024,4) capped at 64 and caused a spill storm (R4).
__global__ __launch_bounds__(1024) void k_main(const int* __restrict__ tokp,
                                               const float* __restrict__ embf,
                                               const float* __restrict__ Af,
                                               const float* __restrict__ b1f,
                                               const float* __restrict__ b2f,
                                               const float* __restrict__ Wo1f,
                                               const float* __restrict__ bo1f,
                                               const float* __restrict__ Wo2f,
                                               float* __restrict__ ws,
                                               float* __restrict__ outp) {
    __shared__ __align__(16) unsigned short w2b[128 * 136];   // 34816 B
    __shared__ __align__(16) unsigned short xo[4 * 136];      // own 4 x-rows, bf16
    __shared__ __align__(16) float red[8][4][128];            // 16384 B (head reuses as rs)
    __shared__ __align__(16) float zs[4][128];                // 2048 B
    __shared__ float a_s[4][128];                             // 2048 B
    __shared__ __align__(16) float hja_s[4][128];             // 2048 B
    __shared__ __align__(16) float hjb_s[4][128];             // 2048 B (publish staging)
    __shared__ __align__(16) float wo1s[128 * 136];           // 69632 B (head only)

    const unsigned short* gw1t = (const unsigned short*)(ws + WS_W1T);
    const unsigned short* gw2b = (const unsigned short*)(ws + WS_W2B);
    int* cnt = (int*)(ws + WS_CNT);

    int blk = blockIdx.x;
    // all 32 blocks of a batch share blk&7 -> same XCD (L2-local barrier + exchange)
    int b = blk & 7, g = blk >> 3, i0 = g * 4;
    int t = threadIdx.x;
    int wave = t >> 6, lane = t & 63;
    int col = lane & 15, quad = lane >> 4;

    // ---- persistent staging (once) ----
    {
        const uint4* s2 = (const uint4*)gw2b; uint4* d2 = (uint4*)w2b;
#pragma unroll
        for (int it = 0; it < 3; ++it) { int idx = it * 1024 + t; if (idx < 2176) d2[idx] = s2[idx]; }
    }
    float b1r = (wave >= 8) ? b1f[(wave - 8) * 16 + col] : 0.f;   // publish cols of this wave
    int we = wave & 1, wj = wave >> 1;
    int ebase = we * 64, jbase = wj * 16;
    float b2r[4];
#pragma unroll
    for (int et = 0; et < 4; ++et) b2r[et] = b2f[ebase + et * 16 + col];

    int ii_own = (t >> 7) & 3, e_own = t & 127, half = t >> 9;
    if (half == 0) a_s[ii_own][e_own] = Af[(b * NN + e_own) * NN + i0 + ii_own];  // A[b, j, i0+ii]
    int trow = tokp[b * NN + i0 + ii_own];
    float xown = embf[trow * DD + e_own];          // owned x element, carried in f32
    if (half == 0) xo[ii_own * 136 + e_own] = f2bf_hw(xown);
    __syncthreads();

    // this wave's W1 fragment row base (nt = wave), reloaded per round (L1/L2-hot)
    const unsigned short* w1row = gw1t + (wave * 16 + col) * 136 + quad * 8;

    for (int r = 0; r < 5; ++r) {
        unsigned short* gbw = (unsigned short*)(ws + ((r & 1) ? WS_HJB1 : WS_HJB0));

        // ---- mini-GEMM1: own 4 rows only (A rows 0..3 = xo, rest zero); nt = wave ----
        {
            bf16x8 w1f[4];
#pragma unroll
            for (int ks = 0; ks < 4; ++ks)
                w1f[ks] = *reinterpret_cast<const bf16x8*>(w1row + ks * 32);
            bf16x8 af[4];
#pragma unroll
            for (int ks = 0; ks < 4; ++ks) {
                bf16x8 z = {0, 0, 0, 0, 0, 0, 0, 0};
                af[ks] = (col < 4) ? *reinterpret_cast<const bf16x8*>(&xo[col * 136 + ks * 32 + quad * 8]) : z;
            }
            floatx4 acc = (floatx4){0.f, 0.f, 0.f, 0.f};
#pragma unroll
            for (int ks = 0; ks < 4; ++ks)
                acc = __builtin_amdgcn_mfma_f32_16x16x32_bf16(af[ks], w1f[ks], acc, 0, 0, 0);
            if (quad == 0) {               // C rows 0..3 live in quad 0 (A rows 4..15 are zero)
                if (wave < 8) {            // hja tiles (n<128): local
#pragma unroll
                    for (int rr = 0; rr < 4; ++rr) hja_s[rr][wave * 16 + col] = acc[rr];
                } else {                   // Hjb(+b1): stage f32 in LDS for coalesced publish
#pragma unroll
                    for (int rr = 0; rr < 4; ++rr)
                        hjb_s[rr][(wave - 8) * 16 + col] = acc[rr] + b1r;
                }
            }
        }
        __syncthreads();
        // ---- coalesced publish: 128B contiguous per wave (proven R2 pattern) ----
        if (half == 0 && !(e_own & 1)) {
            unsigned int pk = f2bf_pk(hjb_s[ii_own][e_own], hjb_s[ii_own][e_own + 1]);
            int row = b * NN + i0 + ii_own;
            __hip_atomic_store((unsigned int*)gbw + row * 64 + (e_own >> 1), pk,
                               __ATOMIC_RELAXED, __HIP_MEMORY_SCOPE_AGENT);
        }
        // ---- per-batch barrier: Hjb complete ----
        __atomic_signal_fence(__ATOMIC_SEQ_CST);
        __builtin_amdgcn_s_waitcnt(0);
        __syncthreads();
        if (t == 0) {
            int* myc = cnt + (b * 5 + r) * 32;
            __hip_atomic_fetch_add(myc, 1, __ATOMIC_RELAXED, __HIP_MEMORY_SCOPE_AGENT);
            while (__hip_atomic_load(myc, __ATOMIC_RELAXED, __HIP_MEMORY_SCOPE_AGENT) < 32)
                __builtin_amdgcn_s_sleep(1);
        }
        __syncthreads();

        // ---- GEMM2: M = relu(hja_i + Hjb_j) @ W2^T; msg = sum_j a_j * M ----
        union U4 { bf16x8 v; unsigned int u[4]; };
        U4 L[4];
        {
            const unsigned short* base0 = gbw + (size_t)(b * NN + jbase + col) * 128 + quad * 8;
            asm volatile(                  // 4x dwordx4: this wave's 16 Hjb j-rows
                "global_load_dwordx4 %0, %4, off sc0 sc1\n\t"
                "global_load_dwordx4 %1, %4, off offset:64 sc0 sc1\n\t"
                "global_load_dwordx4 %2, %4, off offset:128 sc0 sc1\n\t"
                "global_load_dwordx4 %3, %4, off offset:192 sc0 sc1"
                : "=&v"(L[0].v), "=&v"(L[1].v), "=&v"(L[2].v), "=&v"(L[3].v)
                : "v"(base0)
                : "memory");
        }
        bf16x8 bw[4][4];                   // W2 fragments (LDS, hot) — overlaps load latency
#pragma unroll
        for (int et = 0; et < 4; ++et)
#pragma unroll
            for (int ks = 0; ks < 4; ++ks)
                bw[et][ks] = *reinterpret_cast<const bf16x8*>(&w2b[(ebase + et * 16 + col) * 136 + ks * 32 + quad * 8]);
        asm volatile("s_waitcnt vmcnt(0)" ::: "memory");
        __builtin_amdgcn_sched_barrier(0);

#pragma unroll
        for (int ii = 0; ii < 4; ++ii) {
            floatx4 acc2[4];
#pragma unroll
            for (int et = 0; et < 4; ++et) acc2[et] = (floatx4){0.f, 0.f, 0.f, 0.f};
            float ar[4];
#pragma unroll
            for (int rr = 0; rr < 4; ++rr) ar[rr] = a_s[ii][jbase + quad * 4 + rr];
#pragma unroll
            for (int ks = 0; ks < 4; ++ks) {
                int k0 = ks * 32 + quad * 8;
                U4 Ho;
#pragma unroll
                for (int p = 0; p < 4; ++p) {   // H = relu(hja_i + Hjb): unpack-on-the-fly
                    floatx2 hj, ha2, s2;
                    hj.x = __uint_as_float(L[ks].u[p] << 16);
                    hj.y = __uint_as_float(L[ks].u[p] & 0xFFFF0000u);
                    ha2 = *reinterpret_cast<const floatx2*>(&hja_s[ii][k0 + 2 * p]);
                    asm("v_pk_add_f32 %0, %1, %2" : "=v"(s2) : "v"(hj), "v"(ha2));
                    Ho.u[p] = f2bf_pk(fmaxf(s2.x, 0.f), fmaxf(s2.y, 0.f));
                }
#pragma unroll
                for (int et = 0; et < 4; ++et)
                    acc2[et] = __builtin_amdgcn_mfma_f32_16x16x32_bf16(Ho.v, bw[et][ks], acc2[et], 0, 0, 0);
            }
#pragma unroll
            for (int et = 0; et < 4; ++et) {
                float be = b2r[et];
                float s = 0.f;
#pragma unroll
                for (int rr = 0; rr < 4; ++rr)
                    s += ar[rr] * fmaxf(acc2[et][rr] + be, 0.f);
                s += __shfl_xor(s, 16, 64);
                s += __shfl_xor(s, 32, 64);
                if (quad == 0) red[wj][ii][ebase + et * 16 + col] = s;
            }
        }
        __syncthreads();
        // ---- finalize: xown += msg; stash bf16 x for next round's mini-GEMM1 ----
        if (half == 0) {
            float msg = 0.f;
#pragma unroll
            for (int w8 = 0; w8 < 8; ++w8) msg += red[w8][ii_own][e_own];
            xown += msg;
            if (r < 4) xo[ii_own * 136 + e_own] = f2bf_hw(xown);
            else       zs[ii_own][e_own] = xown;
        }
        if (r < 4) __syncthreads();
    }

    // ---- head (own 4 rows) ----
#pragma unroll
    for (int it = 0; it < 4; ++it) {
        int idx4 = it * 1024 + t;                 // 4096 float4s
        int e = idx4 >> 5, d4 = idx4 & 31;
        float4 wv = reinterpret_cast<const float4*>(Wo1f)[idx4];
        *reinterpret_cast<float4*>(&wo1s[e * 136 + d4 * 4]) = wv;
    }
    __syncthreads();
    if (t < 512) {
        int ii = t >> 7, e = t & 127;
        float acc = 0.f;
#pragma unroll
        for (int d4 = 0; d4 < 32; ++d4) {
            float4 w = *reinterpret_cast<const float4*>(&wo1s[e * 136 + d4 * 4]);
            float4 z = *reinterpret_cast<const float4*>(&zs[ii][d4 * 4]);
            acc += w.x * z.x + w.y * z.y + w.z * z.z + w.w * z.w;
        }
        ((float*)red)[ii * 128 + e] = fmaxf(acc + bo1f[e], 0.f);
    }
    __syncthreads();
    if (t < 40) {
        int ii = t / 10, o = t - ii * 10;
        const float* rsrow = (const float*)red + ii * 128;
        const float4* w2r = reinterpret_cast<const float4*>(Wo2f + o * DD);
        float s = 0.f;
#pragma unroll
        for (int e4 = 0; e4 < 32; ++e4) {
            float4 rv = *reinterpret_cast<const float4*>(&rsrow[e4 * 4]);
            float4 wv = w2r[e4];
            s += rv.x * wv.x + rv.y * wv.y + rv.z * wv.z + rv.w * wv.w;
        }
        int row = b * NN + i0 + ii;
        outp[80 + row * 10 + o] = s;             // x_all (8,128,10)
        if (i0 + ii == 0) outp[b * 10 + o] = s;  // out == x_all[:,0,:]
    }
}

extern "C" void kernel_launch(void* const* d_in, const int* in_sizes, int n_in,
                              void* d_out, int out_size, void* d_ws, size_t ws_size,
                              hipStream_t stream) {
    const int*   tok  = (const int*)d_in[0];
    const float* Af   = (const float*)d_in[1];
    const float* embf = (const float*)d_in[2];
    const float* W1f  = (const float*)d_in[3];
    const float* b1f  = (const float*)d_in[4];
    const float* W2f  = (const float*)d_in[5];
    const float* b2f  = (const float*)d_in[6];
    const float* Wo1f = (const float*)d_in[7];
    const float* bo1f = (const float*)d_in[8];
    const float* Wo2f = (const float*)d_in[9];

    float* ws  = (float*)d_ws;
    float* out = (float*)d_out;

    k_init<<<15, 256, 0, stream>>>(W1f, W2f, ws);
    k_main<<<256, 1024, 0, stream>>>(tok, embf, Af, b1f, b2f, Wo1f, bo1f, Wo2f, ws, out);
}

// Round 9
// 141.918 us; speedup vs baseline: 1.5187x; 1.5187x over previous
//
#include <hip/hip_runtime.h>
#include <hip/hip_bf16.h>

#define NN 128
#define DD 128

typedef __attribute__((ext_vector_type(8))) short bf16x8;
typedef __attribute__((ext_vector_type(4))) float floatx4;
typedef __attribute__((ext_vector_type(2))) float floatx2;

__device__ __forceinline__ unsigned short f2bf_hw(float f) {
    unsigned int r;
    asm("v_cvt_pk_bf16_f32 %0, %1, %2" : "=v"(r) : "v"(f), "v"(f));
    return (unsigned short)r;
}

__device__ __forceinline__ unsigned int f2bf_pk(float lo, float hi) {
    unsigned int r;
    asm("v_cvt_pk_bf16_f32 %0, %1, %2" : "=v"(r) : "v"(lo), "v"(hi));
    return r;
}

// ws layout (float units)
#define WS_HJB0 0        // 8*128*128 bf16 = 65536 f   (Hjb exchange ping)
#define WS_HJB1 65536    // (pong)
#define WS_CNT  131072   // 8 batches x 5 rounds x 32 ints (1 cacheline per counter)

// ---------------- K_init: counter zeroing ONLY (weights converted in k_main regs) --------
__global__ __launch_bounds__(256) void k_init(float* __restrict__ ws) {
    int* cnt = (int*)(ws + WS_CNT);
    int t = threadIdx.x;
#pragma unroll
    for (int it = 0; it < 5; ++it) cnt[it * 256 + t] = 0;
}

// ---- K_main: 5 rounds + head. 256 blocks x 512 threads, 4 rows/block, 1 block/CU --------
// PROVEN exchange shape (R0/R1/R2/R5 all passed): 32 blocks/batch, blk&7 batch grouping.
// 512-block variants (R6-R8) fail deterministically — do not revisit without new evidence.
// W1/W2 MFMA fragments converted f32->bf16 once in prologue, held in VGPRs all 5 rounds
// (launch_bounds(512,2) -> 256-VGPR cap; grid=256 means 1 block/CU regardless).
__global__ __launch_bounds__(512, 2) void k_main(const int* __restrict__ tokp,
                                                 const float* __restrict__ embf,
                                                 const float* __restrict__ Af,
                                                 const float* __restrict__ W1f,
                                                 const float* __restrict__ b1f,
                                                 const float* __restrict__ W2f,
                                                 const float* __restrict__ b2f,
                                                 const float* __restrict__ Wo1f,
                                                 const float* __restrict__ bo1f,
                                                 const float* __restrict__ Wo2f,
                                                 float* __restrict__ ws,
                                                 float* __restrict__ outp) {
    __shared__ __align__(16) unsigned short xo[4 * 136];      // own 4 x-rows, bf16
    __shared__ __align__(16) float red[4][4][128];            // 8192 B (head reuses as rs)
    __shared__ __align__(16) float zs[4][128];                // 2048 B
    __shared__ float a_s[4][128];                             // 2048 B
    __shared__ __align__(16) float hja_s[4][128];             // 2048 B
    __shared__ __align__(16) float hjb_s[4][128];             // 2048 B   (total ~17.5 KB)

    int* cnt = (int*)(ws + WS_CNT);

    int blk = blockIdx.x;
    // all 32 blocks of a batch share blk&7 (1 block/CU round-robin -> same-XCD locality)
    int b = blk & 7, g = blk >> 3, i0 = g * 4;
    int t = threadIdx.x;
    int wave = t >> 6, lane = t & 63;
    int col = lane & 15, quad = lane >> 4;
    int we = wave & 1, wj = wave >> 1;
    int ebase = we * 64, jbase = wj * 32;

    union U4 { bf16x8 v; unsigned int u[4]; };

    // ---- prologue: W2 fragments (persistent regs) from f32 global ----
    bf16x8 bw[4][4];
#pragma unroll
    for (int et = 0; et < 4; ++et)
#pragma unroll
        for (int ks = 0; ks < 4; ++ks) {
            const float* p = W2f + (ebase + et * 16 + col) * 128 + ks * 32 + quad * 8;
            float4 lo = *reinterpret_cast<const float4*>(p);
            float4 hi = *reinterpret_cast<const float4*>(p + 4);
            U4 w;
            w.u[0] = f2bf_pk(lo.x, lo.y); w.u[1] = f2bf_pk(lo.z, lo.w);
            w.u[2] = f2bf_pk(hi.x, hi.y); w.u[3] = f2bf_pk(hi.z, hi.w);
            bw[et][ks] = w.v;
        }
    // ---- W1 fragments (persistent regs): n = (wave*2+u)*16+col; W1t[n][d] = W1[n&127][(n>>7)*128+d]
    bf16x8 w1fr[2][4];
#pragma unroll
    for (int u = 0; u < 2; ++u)
#pragma unroll
        for (int ks = 0; ks < 4; ++ks) {
            int n = (wave * 2 + u) * 16 + col;
            const float* p = W1f + (n & 127) * 256 + (n >> 7) * 128 + ks * 32 + quad * 8;
            float4 lo = *reinterpret_cast<const float4*>(p);
            float4 hi = *reinterpret_cast<const float4*>(p + 4);
            U4 w;
            w.u[0] = f2bf_pk(lo.x, lo.y); w.u[1] = f2bf_pk(lo.z, lo.w);
            w.u[2] = f2bf_pk(hi.x, hi.y); w.u[3] = f2bf_pk(hi.z, hi.w);
            w1fr[u][ks] = w.v;
        }

    float b1r[2];
    b1r[0] = (wave >= 4) ? b1f[((wave - 4) * 2 + 0) * 16 + col] : 0.f;
    b1r[1] = (wave >= 4) ? b1f[((wave - 4) * 2 + 1) * 16 + col] : 0.f;
    float b2r[4];
#pragma unroll
    for (int et = 0; et < 4; ++et) b2r[et] = b2f[ebase + et * 16 + col];

    int ii_own = t >> 7, e_own = t & 127;
    a_s[ii_own][e_own] = Af[(b * NN + e_own) * NN + i0 + ii_own];  // A[b, j, i0+ii]
    int trow = tokp[b * NN + i0 + ii_own];
    float xown = embf[trow * DD + e_own];          // owned x element, carried in f32
    xo[ii_own * 136 + e_own] = f2bf_hw(xown);
    __syncthreads();

    for (int r = 0; r < 5; ++r) {
        unsigned short* gbw = (unsigned short*)(ws + ((r & 1) ? WS_HJB1 : WS_HJB0));

        // ---- mini-GEMM1: own 4 rows (A rows 0..3 = xo, rest zero); nt = wave*2+u ----
        {
            bf16x8 af[4];
#pragma unroll
            for (int ks = 0; ks < 4; ++ks) {
                bf16x8 z = {0, 0, 0, 0, 0, 0, 0, 0};
                af[ks] = (col < 4) ? *reinterpret_cast<const bf16x8*>(&xo[col * 136 + ks * 32 + quad * 8]) : z;
            }
            floatx4 acc0 = (floatx4){0.f, 0.f, 0.f, 0.f};
            floatx4 acc1 = (floatx4){0.f, 0.f, 0.f, 0.f};
#pragma unroll
            for (int ks = 0; ks < 4; ++ks) {
                acc0 = __builtin_amdgcn_mfma_f32_16x16x32_bf16(af[ks], w1fr[0][ks], acc0, 0, 0, 0);
                acc1 = __builtin_amdgcn_mfma_f32_16x16x32_bf16(af[ks], w1fr[1][ks], acc1, 0, 0, 0);
            }
            if (quad == 0) {               // C rows 0..3 live in quad 0, regs 0..3
                if (wave < 4) {            // hja tiles (n = 0..127): local
#pragma unroll
                    for (int rr = 0; rr < 4; ++rr) {
                        hja_s[rr][(wave * 2 + 0) * 16 + col] = acc0[rr];
                        hja_s[rr][(wave * 2 + 1) * 16 + col] = acc1[rr];
                    }
                } else {                   // Hjb(+b1) (n = 128..255): stage for publish
#pragma unroll
                    for (int rr = 0; rr < 4; ++rr) {
                        hjb_s[rr][((wave - 4) * 2 + 0) * 16 + col] = acc0[rr] + b1r[0];
                        hjb_s[rr][((wave - 4) * 2 + 1) * 16 + col] = acc1[rr] + b1r[1];
                    }
                }
            }
        }
        __syncthreads();
        // ---- coalesced publish: 128B contiguous per wave ----
        if (!(e_own & 1)) {
            unsigned int pk = f2bf_pk(hjb_s[ii_own][e_own], hjb_s[ii_own][e_own + 1]);
            int row = b * NN + i0 + ii_own;
            __hip_atomic_store((unsigned int*)gbw + row * 64 + (e_own >> 1), pk,
                               __ATOMIC_RELAXED, __HIP_MEMORY_SCOPE_AGENT);
        }
        // ---- per-batch barrier (32 blocks, proven protocol) ----
        __builtin_amdgcn_s_waitcnt(0);
        __syncthreads();
        if (t == 0) {
            int* myc = cnt + (b * 5 + r) * 32;
            __hip_atomic_fetch_add(myc, 1, __ATOMIC_RELAXED, __HIP_MEMORY_SCOPE_AGENT);
            while (__hip_atomic_load(myc, __ATOMIC_RELAXED, __HIP_MEMORY_SCOPE_AGENT) < 32)
                __builtin_amdgcn_s_sleep(1);
        }
        __syncthreads();

        // ---- GEMM2: M = relu(hja_i + Hjb_j) @ W2^T; msg = sum_j a_j * M ----
        U4 L[2][4];
        {
            const unsigned short* base0 = gbw + (size_t)(b * NN + jbase + col) * 128 + quad * 8;
            const unsigned short* base1 = gbw + (size_t)(b * NN + jbase + 16 + col) * 128 + quad * 8;
            asm volatile(                  // 8x dwordx4: this wave's 32 Hjb j-rows
                "global_load_dwordx4 %0, %8, off sc0 sc1\n\t"
                "global_load_dwordx4 %1, %8, off offset:64 sc0 sc1\n\t"
                "global_load_dwordx4 %2, %8, off offset:128 sc0 sc1\n\t"
                "global_load_dwordx4 %3, %8, off offset:192 sc0 sc1\n\t"
                "global_load_dwordx4 %4, %9, off sc0 sc1\n\t"
                "global_load_dwordx4 %5, %9, off offset:64 sc0 sc1\n\t"
                "global_load_dwordx4 %6, %9, off offset:128 sc0 sc1\n\t"
                "global_load_dwordx4 %7, %9, off offset:192 sc0 sc1"
                : "=&v"(L[0][0].v), "=&v"(L[0][1].v), "=&v"(L[0][2].v), "=&v"(L[0][3].v),
                  "=&v"(L[1][0].v), "=&v"(L[1][1].v), "=&v"(L[1][2].v), "=&v"(L[1][3].v)
                : "v"(base0), "v"(base1)
                : "memory");
        }
        asm volatile("s_waitcnt vmcnt(0)" ::: "memory");
        __builtin_amdgcn_sched_barrier(0);

#pragma unroll
        for (int ii = 0; ii < 4; ++ii) {
            floatx4 acc2[2][4];
#pragma unroll
            for (int jt = 0; jt < 2; ++jt)
#pragma unroll
                for (int et = 0; et < 4; ++et) acc2[jt][et] = (floatx4){0.f, 0.f, 0.f, 0.f};
#pragma unroll
            for (int ks = 0; ks < 4; ++ks) {
                int k0 = ks * 32 + quad * 8;
#pragma unroll
                for (int jt = 0; jt < 2; ++jt) {
                    U4 Ho;
#pragma unroll
                    for (int p = 0; p < 4; ++p) {   // H = relu(hja_i + Hjb): unpack-on-the-fly
                        floatx2 hj, ha2, s2;
                        hj.x = __uint_as_float(L[jt][ks].u[p] << 16);
                        hj.y = __uint_as_float(L[jt][ks].u[p] & 0xFFFF0000u);
                        ha2 = *reinterpret_cast<const floatx2*>(&hja_s[ii][k0 + 2 * p]);
                        asm("v_pk_add_f32 %0, %1, %2" : "=v"(s2) : "v"(hj), "v"(ha2));
                        Ho.u[p] = f2bf_pk(fmaxf(s2.x, 0.f), fmaxf(s2.y, 0.f));
                    }
#pragma unroll
                    for (int et = 0; et < 4; ++et)
                        acc2[jt][et] = __builtin_amdgcn_mfma_f32_16x16x32_bf16(Ho.v, bw[et][ks], acc2[jt][et], 0, 0, 0);
                }
            }
#pragma unroll
            for (int et = 0; et < 4; ++et) {
                float be = b2r[et];
                float s = 0.f;
#pragma unroll
                for (int jt = 0; jt < 2; ++jt) {
                    int j0 = jbase + jt * 16 + quad * 4;
#pragma unroll
                    for (int rr = 0; rr < 4; ++rr)
                        s += a_s[ii][j0 + rr] * fmaxf(acc2[jt][et][rr] + be, 0.f);
                }
                s += __shfl_xor(s, 16, 64);
                s += __shfl_xor(s, 32, 64);
                if (quad == 0) red[wj][ii][ebase + et * 16 + col] = s;
            }
        }
        __syncthreads();
        // ---- finalize: xown += msg; stash bf16 x for next round's mini-GEMM1 ----
        {
            float msg = red[0][ii_own][e_own] + red[1][ii_own][e_own]
                      + red[2][ii_own][e_own] + red[3][ii_own][e_own];
            xown += msg;
            if (r < 4) xo[ii_own * 136 + e_own] = f2bf_hw(xown);
            else       zs[ii_own][e_own] = xown;
        }
        __syncthreads();   // r<4: xo ready for next mini-GEMM1; r==4: zs ready for head
    }

    // ---- head (own 4 rows); Wo1 read from global (L2/L3-hot: all blocks share it) ----
    {
        const float4* wrow = reinterpret_cast<const float4*>(Wo1f + e_own * 128);
        float acc = 0.f;
#pragma unroll
        for (int d4 = 0; d4 < 32; ++d4) {
            float4 w = wrow[d4];
            float4 z = *reinterpret_cast<const float4*>(&zs[ii_own][d4 * 4]);
            acc += w.x * z.x + w.y * z.y + w.z * z.z + w.w * z.w;
        }
        ((float*)red)[ii_own * 128 + e_own] = fmaxf(acc + bo1f[e_own], 0.f);
    }
    __syncthreads();
    if (t < 40) {
        int ii = t / 10, o = t - ii * 10;
        const float* rsrow = (const float*)red + ii * 128;
        const float4* w2r = reinterpret_cast<const float4*>(Wo2f + o * DD);
        float s = 0.f;
#pragma unroll
        for (int e4 = 0; e4 < 32; ++e4) {
            float4 rv = *reinterpret_cast<const float4*>(&rsrow[e4 * 4]);
            float4 wv = w2r[e4];
            s += rv.x * wv.x + rv.y * wv.y + rv.z * wv.z + rv.w * wv.w;
        }
        int row = b * NN + i0 + ii;
        outp[80 + row * 10 + o] = s;             // x_all (8,128,10)
        if (i0 + ii == 0) outp[b * 10 + o] = s;  // out == x_all[:,0,:]
    }
}

extern "C" void kernel_launch(void* const* d_in, const int* in_sizes, int n_in,
                              void* d_out, int out_size, void* d_ws, size_t ws_size,
                              hipStream_t stream) {
    const int*   tok  = (const int*)d_in[0];
    const float* Af   = (const float*)d_in[1];
    const float* embf = (const float*)d_in[2];
    const float* W1f  = (const float*)d_in[3];
    const float* b1f  = (const float*)d_in[4];
    const float* W2f  = (const float*)d_in[5];
    const float* b2f  = (const float*)d_in[6];
    const float* Wo1f = (const float*)d_in[7];
    const float* bo1f = (const float*)d_in[8];
    const float* Wo2f = (const float*)d_in[9];

    float* ws  = (float*)d_ws;
    float* out = (float*)d_out;

    k_init<<<1, 256, 0, stream>>>(ws);
    k_main<<<256, 512, 0, stream>>>(tok, embf, Af, W1f, b1f, W2f, b2f, Wo1f, bo1f, Wo2f, ws, out);
}

// Round 10
// 141.753 us; speedup vs baseline: 1.5204x; 1.0012x over previous
//
#include <hip/hip_runtime.h>
#include <hip/hip_bf16.h>

#define NN 128
#define DD 128

typedef __attribute__((ext_vector_type(8))) short bf16x8;
typedef __attribute__((ext_vector_type(4))) float floatx4;
typedef __attribute__((ext_vector_type(2))) float floatx2;

__device__ __forceinline__ unsigned short f2bf_hw(float f) {
    unsigned int r;
    asm("v_cvt_pk_bf16_f32 %0, %1, %2" : "=v"(r) : "v"(f), "v"(f));
    return (unsigned short)r;
}

__device__ __forceinline__ unsigned int f2bf_pk(float lo, float hi) {
    unsigned int r;
    asm("v_cvt_pk_bf16_f32 %0, %1, %2" : "=v"(r) : "v"(lo), "v"(hi));
    return r;
}

// ws layout (float units)
#define WS_HJB0 0        // 8*128*128 bf16 = 65536 f   (Hjb exchange ping)
#define WS_HJB1 65536    // (pong)
#define WS_FLG  131072   // 8 batches x 32 ints (one 128B flag line per batch, round tags)

// ---------------- K_init: flag zeroing ONLY ----------------
__global__ __launch_bounds__(256) void k_init(float* __restrict__ ws) {
    int* fl = (int*)(ws + WS_FLG);
    if (threadIdx.x < 256) fl[threadIdx.x] = 0;
}

// ---- K_main: 5 rounds + head. 256 blocks x 512 threads, 4 rows/block, 1 block/CU --------
// Exchange cost measured at ~10-12 us/round (R9: 5 barriers = 87us vs R2: 4 barriers = 73.5).
// This version: round 0 from in-block token tables (no barrier), rounds 1-4 via flag-line
// barrier (parallel stores + one 128B poll load) instead of 32 serialized atomic RMWs.
__global__ __launch_bounds__(512, 2) void k_main(const int* __restrict__ tokp,
                                                 const float* __restrict__ embf,
                                                 const float* __restrict__ Af,
                                                 const float* __restrict__ W1f,
                                                 const float* __restrict__ b1f,
                                                 const float* __restrict__ W2f,
                                                 const float* __restrict__ b2f,
                                                 const float* __restrict__ Wo1f,
                                                 const float* __restrict__ bo1f,
                                                 const float* __restrict__ Wo2f,
                                                 float* __restrict__ ws,
                                                 float* __restrict__ outp) {
    __shared__ __align__(16) unsigned short xo[4 * 136];      // own 4 x-rows, bf16
    __shared__ __align__(16) float red[4][4][128];            // 8192 B (head reuses as rs)
    __shared__ __align__(16) float zs[4][128];                // 2048 B
    __shared__ float a_s[4][128];                             // 2048 B
    __shared__ __align__(16) float hja_s[4][128];             // 2048 B
    __shared__ __align__(16) float hjb_s[4][128];             // 2048 B
    __shared__ __align__(16) float tabA[14 * 128];            // 7168 B  (round-0 hja table)
    __shared__ __align__(16) unsigned short tabB[14 * 128];   // 3584 B  (round-0 Hjb table)
    __shared__ int tokj[128];                                 // 512 B   (~29 KB total)

    int* flg = (int*)(ws + WS_FLG);

    int blk = blockIdx.x;
    int b = blk & 7, g = blk >> 3, i0 = g * 4;                // 32 blocks/batch, 1/CU
    int t = threadIdx.x;
    int wave = t >> 6, lane = t & 63;
    int col = lane & 15, quad = lane >> 4;
    int we = wave & 1, wj = wave >> 1;
    int ebase = we * 64, jbase = wj * 32;

    union U4 { bf16x8 v; unsigned int u[4]; };

    // ---- prologue: W2 fragments (persistent regs) from f32 global ----
    bf16x8 bw[4][4];
#pragma unroll
    for (int et = 0; et < 4; ++et)
#pragma unroll
        for (int ks = 0; ks < 4; ++ks) {
            const float* p = W2f + (ebase + et * 16 + col) * 128 + ks * 32 + quad * 8;
            float4 lo = *reinterpret_cast<const float4*>(p);
            float4 hi = *reinterpret_cast<const float4*>(p + 4);
            U4 w;
            w.u[0] = f2bf_pk(lo.x, lo.y); w.u[1] = f2bf_pk(lo.z, lo.w);
            w.u[2] = f2bf_pk(hi.x, hi.y); w.u[3] = f2bf_pk(hi.z, hi.w);
            bw[et][ks] = w.v;
        }
    // ---- W1 fragments (persistent regs): n = (wave*2+u)*16+col ----
    bf16x8 w1fr[2][4];
#pragma unroll
    for (int u = 0; u < 2; ++u)
#pragma unroll
        for (int ks = 0; ks < 4; ++ks) {
            int n = (wave * 2 + u) * 16 + col;
            const float* p = W1f + (n & 127) * 256 + (n >> 7) * 128 + ks * 32 + quad * 8;
            float4 lo = *reinterpret_cast<const float4*>(p);
            float4 hi = *reinterpret_cast<const float4*>(p + 4);
            U4 w;
            w.u[0] = f2bf_pk(lo.x, lo.y); w.u[1] = f2bf_pk(lo.z, lo.w);
            w.u[2] = f2bf_pk(hi.x, hi.y); w.u[3] = f2bf_pk(hi.z, hi.w);
            w1fr[u][ks] = w.v;
        }

    float b1r[2];
    b1r[0] = (wave >= 4) ? b1f[((wave - 4) * 2 + 0) * 16 + col] : 0.f;
    b1r[1] = (wave >= 4) ? b1f[((wave - 4) * 2 + 1) * 16 + col] : 0.f;
    float b2r[4];
#pragma unroll
    for (int et = 0; et < 4; ++et) b2r[et] = b2f[ebase + et * 16 + col];

    int ii_own = t >> 7, e_own = t & 127;
    a_s[ii_own][e_own] = Af[(b * NN + e_own) * NN + i0 + ii_own];  // A[b, j, i0+ii]
    if (t < 128) tokj[t] = tokp[b * NN + t];
    int trow = tokp[b * NN + i0 + ii_own];
    float xown = embf[trow * DD + e_own];          // owned x element, carried in f32

    // ---- round-0 token tables: proj[v][n] for v=0..13 via the SAME MFMA as mini-GEMM1 ----
    {
        bf16x8 afT[4];
#pragma unroll
        for (int ks = 0; ks < 4; ++ks) {
            bf16x8 z = {0, 0, 0, 0, 0, 0, 0, 0};
            if (col < 14) {
                const float* p = embf + col * 128 + ks * 32 + quad * 8;
                float4 lo = *reinterpret_cast<const float4*>(p);
                float4 hi = *reinterpret_cast<const float4*>(p + 4);
                U4 w;
                w.u[0] = f2bf_pk(lo.x, lo.y); w.u[1] = f2bf_pk(lo.z, lo.w);
                w.u[2] = f2bf_pk(hi.x, hi.y); w.u[3] = f2bf_pk(hi.z, hi.w);
                afT[ks] = w.v;
            } else afT[ks] = z;
        }
        floatx4 ta0 = (floatx4){0.f, 0.f, 0.f, 0.f};
        floatx4 ta1 = (floatx4){0.f, 0.f, 0.f, 0.f};
#pragma unroll
        for (int ks = 0; ks < 4; ++ks) {
            ta0 = __builtin_amdgcn_mfma_f32_16x16x32_bf16(afT[ks], w1fr[0][ks], ta0, 0, 0, 0);
            ta1 = __builtin_amdgcn_mfma_f32_16x16x32_bf16(afT[ks], w1fr[1][ks], ta1, 0, 0, 0);
        }
        if (wave < 4) {                    // n<128 -> tabA (f32), C rows = token value
            int n0 = (wave * 2 + 0) * 16 + col, n1 = (wave * 2 + 1) * 16 + col;
#pragma unroll
            for (int rr = 0; rr < 4; ++rr) {
                int v = quad * 4 + rr;
                if (v < 14) { tabA[v * 128 + n0] = ta0[rr]; tabA[v * 128 + n1] = ta1[rr]; }
            }
        } else {                           // n>=128 -> tabB (bf16 pairs, +b1)
            int d0 = ((wave - 4) * 2 + 0) * 16 + col, d1 = ((wave - 4) * 2 + 1) * 16 + col;
#pragma unroll
            for (int rr = 0; rr < 4; ++rr) {
                float v0 = ta0[rr] + b1r[0]; float p0 = __shfl_xor(v0, 1, 64);
                float v1 = ta1[rr] + b1r[1]; float p1 = __shfl_xor(v1, 1, 64);
                int v = quad * 4 + rr;
                if (!(col & 1) && v < 14) {
                    ((unsigned int*)tabB)[v * 64 + (d0 >> 1)] = f2bf_pk(v0, p0);
                    ((unsigned int*)tabB)[v * 64 + (d1 >> 1)] = f2bf_pk(v1, p1);
                }
            }
        }
    }
    __syncthreads();

    for (int r = 0; r < 5; ++r) {
        unsigned short* gbw = (unsigned short*)(ws + ((r & 1) ? WS_HJB1 : WS_HJB0));
        U4 L[2][4];

        if (r == 0) {
            // ---- round 0: hja/Hjb from token tables — NO publish, NO barrier ----
            hja_s[ii_own][e_own] = tabA[trow * 128 + e_own];
            __syncthreads();
            int tv0 = tokj[jbase + col], tv1 = tokj[jbase + 16 + col];
#pragma unroll
            for (int ks = 0; ks < 4; ++ks) {
                L[0][ks].v = *reinterpret_cast<const bf16x8*>(&tabB[tv0 * 128 + ks * 32 + quad * 8]);
                L[1][ks].v = *reinterpret_cast<const bf16x8*>(&tabB[tv1 * 128 + ks * 32 + quad * 8]);
            }
        } else {
            // ---- mini-GEMM1: own 4 rows (A rows 0..3 = xo, rest zero); nt = wave*2+u ----
            {
                bf16x8 af[4];
#pragma unroll
                for (int ks = 0; ks < 4; ++ks) {
                    bf16x8 z = {0, 0, 0, 0, 0, 0, 0, 0};
                    af[ks] = (col < 4) ? *reinterpret_cast<const bf16x8*>(&xo[col * 136 + ks * 32 + quad * 8]) : z;
                }
                floatx4 acc0 = (floatx4){0.f, 0.f, 0.f, 0.f};
                floatx4 acc1 = (floatx4){0.f, 0.f, 0.f, 0.f};
#pragma unroll
                for (int ks = 0; ks < 4; ++ks) {
                    acc0 = __builtin_amdgcn_mfma_f32_16x16x32_bf16(af[ks], w1fr[0][ks], acc0, 0, 0, 0);
                    acc1 = __builtin_amdgcn_mfma_f32_16x16x32_bf16(af[ks], w1fr[1][ks], acc1, 0, 0, 0);
                }
                if (quad == 0) {           // C rows 0..3 live in quad 0, regs 0..3
                    if (wave < 4) {
#pragma unroll
                        for (int rr = 0; rr < 4; ++rr) {
                            hja_s[rr][(wave * 2 + 0) * 16 + col] = acc0[rr];
                            hja_s[rr][(wave * 2 + 1) * 16 + col] = acc1[rr];
                        }
                    } else {
#pragma unroll
                        for (int rr = 0; rr < 4; ++rr) {
                            hjb_s[rr][((wave - 4) * 2 + 0) * 16 + col] = acc0[rr] + b1r[0];
                            hjb_s[rr][((wave - 4) * 2 + 1) * 16 + col] = acc1[rr] + b1r[1];
                        }
                    }
                }
            }
            __syncthreads();
            // ---- coalesced publish: 128B contiguous per wave ----
            if (!(e_own & 1)) {
                unsigned int pk = f2bf_pk(hjb_s[ii_own][e_own], hjb_s[ii_own][e_own + 1]);
                int row = b * NN + i0 + ii_own;
                __hip_atomic_store((unsigned int*)gbw + row * 64 + (e_own >> 1), pk,
                                   __ATOMIC_RELAXED, __HIP_MEMORY_SCOPE_AGENT);
            }
            // ---- flag-line barrier: parallel stores, one 128B poll load ----
            __builtin_amdgcn_s_waitcnt(0);     // this wave's stores drained
            __syncthreads();                   // all waves' stores drained
            {
                int* fl = flg + b * 32;
                if (t == g)                    // g < 32, lane g of wave 0
                    __hip_atomic_store(fl + g, r, __ATOMIC_RELAXED, __HIP_MEMORY_SCOPE_AGENT);
                if (t < 64) {
                    while (true) {
                        int v = (t < 32) ? __hip_atomic_load(fl + t, __ATOMIC_RELAXED,
                                                             __HIP_MEMORY_SCOPE_AGENT) : r;
                        if (__all(v >= r)) break;
                        __builtin_amdgcn_s_sleep(1);
                    }
                }
                __syncthreads();
            }
            // ---- load this wave's 32 Hjb j-rows ----
            {
                const unsigned short* base0 = gbw + (size_t)(b * NN + jbase + col) * 128 + quad * 8;
                const unsigned short* base1 = gbw + (size_t)(b * NN + jbase + 16 + col) * 128 + quad * 8;
                asm volatile(
                    "global_load_dwordx4 %0, %8, off sc0 sc1\n\t"
                    "global_load_dwordx4 %1, %8, off offset:64 sc0 sc1\n\t"
                    "global_load_dwordx4 %2, %8, off offset:128 sc0 sc1\n\t"
                    "global_load_dwordx4 %3, %8, off offset:192 sc0 sc1\n\t"
                    "global_load_dwordx4 %4, %9, off sc0 sc1\n\t"
                    "global_load_dwordx4 %5, %9, off offset:64 sc0 sc1\n\t"
                    "global_load_dwordx4 %6, %9, off offset:128 sc0 sc1\n\t"
                    "global_load_dwordx4 %7, %9, off offset:192 sc0 sc1"
                    : "=&v"(L[0][0].v), "=&v"(L[0][1].v), "=&v"(L[0][2].v), "=&v"(L[0][3].v),
                      "=&v"(L[1][0].v), "=&v"(L[1][1].v), "=&v"(L[1][2].v), "=&v"(L[1][3].v)
                    : "v"(base0), "v"(base1)
                    : "memory");
                asm volatile("s_waitcnt vmcnt(0)" ::: "memory");
                __builtin_amdgcn_sched_barrier(0);
            }
        }

        // ---- GEMM2: M = relu(hja_i + Hjb_j) @ W2^T; msg = sum_j a_j * M ----
#pragma unroll
        for (int ii = 0; ii < 4; ++ii) {
            floatx4 acc2[2][4];
#pragma unroll
            for (int jt = 0; jt < 2; ++jt)
#pragma unroll
                for (int et = 0; et < 4; ++et) acc2[jt][et] = (floatx4){0.f, 0.f, 0.f, 0.f};
#pragma unroll
            for (int ks = 0; ks < 4; ++ks) {
                int k0 = ks * 32 + quad * 8;
#pragma unroll
                for (int jt = 0; jt < 2; ++jt) {
                    U4 Ho;
#pragma unroll
                    for (int p = 0; p < 4; ++p) {   // H = relu(hja_i + Hjb): unpack-on-the-fly
                        floatx2 hj, ha2, s2;
                        hj.x = __uint_as_float(L[jt][ks].u[p] << 16);
                        hj.y = __uint_as_float(L[jt][ks].u[p] & 0xFFFF0000u);
                        ha2 = *reinterpret_cast<const floatx2*>(&hja_s[ii][k0 + 2 * p]);
                        asm("v_pk_add_f32 %0, %1, %2" : "=v"(s2) : "v"(hj), "v"(ha2));
                        Ho.u[p] = f2bf_pk(fmaxf(s2.x, 0.f), fmaxf(s2.y, 0.f));
                    }
#pragma unroll
                    for (int et = 0; et < 4; ++et)
                        acc2[jt][et] = __builtin_amdgcn_mfma_f32_16x16x32_bf16(Ho.v, bw[et][ks], acc2[jt][et], 0, 0, 0);
                }
            }
#pragma unroll
            for (int et = 0; et < 4; ++et) {
                float be = b2r[et];
                float s = 0.f;
#pragma unroll
                for (int jt = 0; jt < 2; ++jt) {
                    int j0 = jbase + jt * 16 + quad * 4;
#pragma unroll
                    for (int rr = 0; rr < 4; ++rr)
                        s += a_s[ii][j0 + rr] * fmaxf(acc2[jt][et][rr] + be, 0.f);
                }
                s += __shfl_xor(s, 16, 64);
                s += __shfl_xor(s, 32, 64);
                if (quad == 0) red[wj][ii][ebase + et * 16 + col] = s;
            }
        }
        __syncthreads();
        // ---- finalize: xown += msg; stash bf16 x for next round's mini-GEMM1 ----
        {
            float msg = red[0][ii_own][e_own] + red[1][ii_own][e_own]
                      + red[2][ii_own][e_own] + red[3][ii_own][e_own];
            xown += msg;
            if (r < 4) xo[ii_own * 136 + e_own] = f2bf_hw(xown);
            else       zs[ii_own][e_own] = xown;
        }
        __syncthreads();   // r<4: xo ready for next mini-GEMM1; r==4: zs ready for head
    }

    // ---- head (own 4 rows); Wo1 read from global (L2/L3-hot: all blocks share it) ----
    {
        const float4* wrow = reinterpret_cast<const float4*>(Wo1f + e_own * 128);
        float acc = 0.f;
#pragma unroll
        for (int d4 = 0; d4 < 32; ++d4) {
            float4 w = wrow[d4];
            float4 z = *reinterpret_cast<const float4*>(&zs[ii_own][d4 * 4]);
            acc += w.x * z.x + w.y * z.y + w.z * z.z + w.w * z.w;
        }
        ((float*)red)[ii_own * 128 + e_own] = fmaxf(acc + bo1f[e_own], 0.f);
    }
    __syncthreads();
    if (t < 40) {
        int ii = t / 10, o = t - ii * 10;
        const float* rsrow = (const float*)red + ii * 128;
        const float4* w2r = reinterpret_cast<const float4*>(Wo2f + o * DD);
        float s = 0.f;
#pragma unroll
        for (int e4 = 0; e4 < 32; ++e4) {
            float4 rv = *reinterpret_cast<const float4*>(&rsrow[e4 * 4]);
            float4 wv = w2r[e4];
            s += rv.x * wv.x + rv.y * wv.y + rv.z * wv.z + rv.w * wv.w;
        }
        int row = b * NN + i0 + ii;
        outp[80 + row * 10 + o] = s;             // x_all (8,128,10)
        if (i0 + ii == 0) outp[b * 10 + o] = s;  // out == x_all[:,0,:]
    }
}

extern "C" void kernel_launch(void* const* d_in, const int* in_sizes, int n_in,
                              void* d_out, int out_size, void* d_ws, size_t ws_size,
                              hipStream_t stream) {
    const int*   tok  = (const int*)d_in[0];
    const float* Af   = (const float*)d_in[1];
    const float* embf = (const float*)d_in[2];
    const float* W1f  = (const float*)d_in[3];
    const float* b1f  = (const float*)d_in[4];
    const float* W2f  = (const float*)d_in[5];
    const float* b2f  = (const float*)d_in[6];
    const float* Wo1f = (const float*)d_in[7];
    const float* bo1f = (const float*)d_in[8];
    const float* Wo2f = (const float*)d_in[9];

    float* ws  = (float*)d_ws;
    float* out = (float*)d_out;

    k_init<<<1, 256, 0, stream>>>(ws);
    k_main<<<256, 512, 0, stream>>>(tok, embf, Af, W1f, b1f, W2f, b2f, Wo1f, bo1f, Wo2f, ws, out);
}